// Round 7
// baseline (361.195 us; speedup 1.0000x reference)
//
#include <hip/hip_runtime.h>
#include <math.h>

typedef __attribute__((ext_vector_type(8))) short short8;
typedef __attribute__((ext_vector_type(4))) float f32x4;

constexpr int CB = 8, CL = 1024, CD = 1024, CDH = 128, CM = 8192;
constexpr float CSCALE = 0.25f;   // (DH//H)^-0.5 = 16^-0.5
constexpr float CEPS = 1e-5f;

__device__ inline ushort f2b(float f) {
    union { float f; unsigned u; } v; v.f = f;
    unsigned r = v.u + 0x7FFF + ((v.u >> 16) & 1);   // RNE
    return (ushort)(r >> 16);
}
__device__ inline float b2f(ushort u) {
    union { unsigned u; float f; } v; v.u = ((unsigned)u) << 16;
    return v.f;
}

// async 16B/lane global->LDS (wave-uniform base + lane*16 dest)
__device__ inline void gld16(const void* g, void* l) {
    __builtin_amdgcn_global_load_lds(
        (const __attribute__((address_space(1))) void*)g,
        (__attribute__((address_space(3))) void*)l, 16, 0, 0);
}

// ---------------------------------------------------------------- gather ----
// Writes ONLY bf16 xb; the fp32 residual is re-gathered from emb in
// k_gemm_out (bit-identical: x[row] == emb[tokens[row]]).
__global__ __launch_bounds__(256) void k_gather(const int* __restrict__ tokens,
                                                const float* __restrict__ emb,
                                                ushort* __restrict__ xb) {
    int row = blockIdx.x;
    int tok = tokens[row];
    float4 v = ((const float4*)(emb + (size_t)tok * CD))[threadIdx.x];
    ushort4 o; o.x = f2b(v.x); o.y = f2b(v.y); o.z = f2b(v.z); o.w = f2b(v.w);
    ((ushort4*)(xb + (size_t)row * CD))[threadIdx.x] = o;
}

// -------------------------------------- weight transpose f32->bf16 (x4) -----
__global__ __launch_bounds__(256) void k_wtrans(const float* __restrict__ W0,
                                                const float* __restrict__ W1,
                                                const float* __restrict__ W2,
                                                const float* __restrict__ W3,
                                                ushort* __restrict__ Wt) {
    __shared__ float ws_[32][33];
    const int z = blockIdx.z;
    const float* W = (z == 0) ? W0 : ((z == 1) ? W1 : ((z == 2) ? W2 : W3));
    ushort* Wtz = Wt + (size_t)z * CD * CD;
    const int tk = blockIdx.x * 32, tn = blockIdx.y * 32;
    const int t = threadIdx.x;
    {
        int r = t >> 3, c4 = (t & 7) * 4;
        *(float4*)&ws_[r][c4] = *(const float4*)&W[(size_t)(tk + r) * CD + tn + c4];
    }
    __syncthreads();
    int n = t >> 3, k4 = (t & 7) * 4;
    ushort4 o;
    o.x = f2b(ws_[k4 + 0][n]); o.y = f2b(ws_[k4 + 1][n]);
    o.z = f2b(ws_[k4 + 2][n]); o.w = f2b(ws_[k4 + 3][n]);
    *(ushort4*)&Wtz[(size_t)(tn + n) * CD + tk + k4] = o;
}

// ---------------------------------------------------------- bf16 MFMA GEMM --
// R0-proven structure + R6-verified XCD remap (XCD = blockIdx.x owns 8
// m-tiles x all n: weights L2-resident per XCD, each A-panel fetched once).
__global__ __launch_bounds__(256) void k_gemm_qkv(const ushort* __restrict__ A,
                                                  const ushort* __restrict__ Wt3,
                                                  const float* __restrict__ b0,
                                                  const float* __restrict__ b1,
                                                  const float* __restrict__ b2,
                                                  ushort* __restrict__ C3) {
    __shared__ ushort As[128 * 32];
    __shared__ ushort Bs[128 * 32];
    const int z = blockIdx.z;
    const ushort* Bt  = Wt3 + (size_t)z * CD * CD;
    const float* bias = (z == 0) ? b0 : ((z == 1) ? b1 : b2);
    ushort* Cout      = C3 + (size_t)z * CM * CD;

    const int t = threadIdx.x, w = t >> 6, l = t & 63;
    const int lane15 = l & 15, quad = l >> 4;
    const int bm = (blockIdx.x * 8 + (blockIdx.y >> 3)) * 128;   // XCD-local A rows
    const int bn = (blockIdx.y & 7) * 128;                       // all n per XCD
    const int wm = (w >> 1) * 64, wn = (w & 1) * 64;
    const int arow = l >> 2;
    const int aseg = (l & 3) * 8;
    f32x4 acc[4][4] = {};

    for (int k0 = 0; k0 < CD; k0 += 32) {
        __syncthreads();
        #pragma unroll
        for (int c2 = 0; c2 < 2; ++c2) {
            int c = w * 2 + c2;
            gld16(A  + (size_t)(bm + c * 16 + arow) * CD + k0 + aseg, &As[c * 512 + l * 8]);
            gld16(Bt + (size_t)(bn + c * 16 + arow) * CD + k0 + aseg, &Bs[c * 512 + l * 8]);
        }
        __syncthreads();
        short8 af[4], bf[4];
        #pragma unroll
        for (int im = 0; im < 4; ++im)
            af[im] = *(const short8*)&As[(wm + im * 16 + lane15) * 32 + quad * 8];
        #pragma unroll
        for (int in = 0; in < 4; ++in)
            bf[in] = *(const short8*)&Bs[(wn + in * 16 + lane15) * 32 + quad * 8];
        #pragma unroll
        for (int im = 0; im < 4; ++im)
            #pragma unroll
            for (int in = 0; in < 4; ++in)
                acc[im][in] = __builtin_amdgcn_mfma_f32_16x16x32_bf16(af[im], bf[in], acc[im][in], 0, 0, 0);
    }
    #pragma unroll
    for (int in = 0; in < 4; ++in) {
        int col = bn + wn + in * 16 + lane15;
        float bv = bias[col];
        #pragma unroll
        for (int im = 0; im < 4; ++im) {
            int row0 = bm + wm + im * 16 + quad * 4;
            #pragma unroll
            for (int r = 0; r < 4; ++r)
                Cout[(size_t)(row0 + r) * CD + col] = f2b(acc[im][in][r] + bv);
        }
    }
}

// OUT-projection, fused residual/pooling epilogue. Residual is re-gathered
// from emb via a 128-entry token LUT (bit-identical to the old x buffer).
__global__ __launch_bounds__(256) void k_gemm_out(const ushort* __restrict__ A,
                                                  const ushort* __restrict__ Bt,
                                                  const float* __restrict__ bias,
                                                  const int* __restrict__ tokens,
                                                  const float* __restrict__ emb,
                                                  float* __restrict__ pmax,
                                                  float* __restrict__ psum) {
    __shared__ ushort As[128 * 32];
    __shared__ ushort Bs[128 * 32];
    __shared__ float redmx[4][64], redsm[4][64];
    __shared__ int tokL[128];
    const int t = threadIdx.x, w = t >> 6, l = t & 63;
    const int lane15 = l & 15, quad = l >> 4;
    const int bm = (blockIdx.x * 8 + (blockIdx.y >> 3)) * 128;
    const int bn = (blockIdx.y & 7) * 128;
    const int wm = (w >> 1) * 64, wn = (w & 1) * 64;
    const int arow = l >> 2;
    const int aseg = (l & 3) * 8;
    if (t < 128) tokL[t] = tokens[bm + t];   // covered by first k-loop barrier
    f32x4 acc[4][4] = {};

    for (int k0 = 0; k0 < CD; k0 += 32) {
        __syncthreads();
        #pragma unroll
        for (int c2 = 0; c2 < 2; ++c2) {
            int c = w * 2 + c2;
            gld16(A  + (size_t)(bm + c * 16 + arow) * CD + k0 + aseg, &As[c * 512 + l * 8]);
            gld16(Bt + (size_t)(bn + c * 16 + arow) * CD + k0 + aseg, &Bs[c * 512 + l * 8]);
        }
        __syncthreads();
        short8 af[4], bf[4];
        #pragma unroll
        for (int im = 0; im < 4; ++im)
            af[im] = *(const short8*)&As[(wm + im * 16 + lane15) * 32 + quad * 8];
        #pragma unroll
        for (int in = 0; in < 4; ++in)
            bf[in] = *(const short8*)&Bs[(wn + in * 16 + lane15) * 32 + quad * 8];
        #pragma unroll
        for (int im = 0; im < 4; ++im)
            #pragma unroll
            for (int in = 0; in < 4; ++in)
                acc[im][in] = __builtin_amdgcn_mfma_f32_16x16x32_bf16(af[im], bf[in], acc[im][in], 0, 0, 0);
    }
    // fused epilogue: per-column max/sum over this block's 128 rows
    const int by = bm >> 7, bb = by >> 3, chunk = by & 7;   // logical m-tile
    float vmax_[4], vsum_[4];
    #pragma unroll
    for (int in = 0; in < 4; ++in) {
        int col = bn + wn + in * 16 + lane15;
        float bvv = bias[col];
        float mx = -3.4e38f, sm = 0.f;
        #pragma unroll
        for (int im = 0; im < 4; ++im) {
            int rl0 = wm + im * 16 + quad * 4;
            #pragma unroll
            for (int r = 0; r < 4; ++r) {
                float rv = emb[(size_t)tokL[rl0 + r] * CD + col];
                float rel = acc[im][in][r] + bvv + rv;
                mx = fmaxf(mx, rel);
                sm += rel;
            }
        }
        mx = fmaxf(mx, __shfl_xor(mx, 16));   // reduce across quads: 64 rows/wave
        mx = fmaxf(mx, __shfl_xor(mx, 32));
        sm += __shfl_xor(sm, 16);
        sm += __shfl_xor(sm, 32);
        vmax_[in] = mx; vsum_[in] = sm;
    }
    if (l < 16) {
        #pragma unroll
        for (int in = 0; in < 4; ++in) {
            redmx[w][in * 16 + lane15] = vmax_[in];
            redsm[w][in * 16 + lane15] = vsum_[in];
        }
    }
    __syncthreads();
    if (t < 128) {                            // combine wave pairs {0,2},{1,3}
        int wcol = t >> 6, cc = t & 63;
        float m = fmaxf(redmx[wcol][cc], redmx[wcol + 2][cc]);
        float s = redsm[wcol][cc] + redsm[wcol + 2][cc];
        size_t off2 = ((size_t)bb * 8 + chunk) * CD + bn + wcol * 64 + cc;
        pmax[off2] = m;
        psum[off2] = s;
    }
}

// ----------------------------------- V -> fragment-ordered planes ----------
__global__ __launch_bounds__(256) void k_vtransp(const ushort* __restrict__ v,
                                                 ushort* __restrict__ Vtp) {
    __shared__ ushort Vs[64 * 136];
    const int i = blockIdx.x >> 4, kt = blockIdx.x & 15;
    const ushort* src = v + (size_t)i * 131072 + (size_t)kt * 64 * 128;
    const int t = threadIdx.x;
    #pragma unroll
    for (int ii = 0; ii < 4; ++ii) {
        int idx = t + 256 * ii;           // vec8 unit 0..1023
        int key = idx >> 4, seg = idx & 15;
        *(uint4*)&Vs[key * 136 + seg * 8] = *(const uint4*)&src[key * 128 + seg * 8];
    }
    __syncthreads();
    ushort* dst = Vtp + (size_t)blockIdx.x * 8192;   // 16 planes * 512
    #pragma unroll
    for (int it = 0; it < 4; ++it) {
        int L = t + 256 * it;             // line 0..1023 = p*64 + cell
        int cell = L & 63;
        int quadk = cell >> 4, l15 = cell & 15;
        int p = L >> 6;
        int d = (p >> 1) * 16 + l15;
        int kb = ((p & 1) * 4 + quadk) * 8;
        uint pk[4];
        #pragma unroll
        for (int jj = 0; jj < 4; ++jj) {
            uint lo = Vs[(kb + 2 * jj) * 136 + d];
            uint hi = Vs[(kb + 2 * jj + 1) * 136 + d];
            pk[jj] = lo | (hi << 16);
        }
        *(uint4*)&dst[(size_t)L * 8] = *(uint4*)pk;
    }
}

// ------------------------------------------------- flash MFMA attention -----
// 4 waves x 32 q-rows; K double-buffered in LDS (cross-wave shared planes),
// V read DIRECTLY from Vtp (per-lane linear: LDS added no sharing for V,
// only capacity cost). LDS 32+8.7+2 = 42.7 KB -> 3 blocks/CU if VGPR allows.
__device__ inline void attn_stageK(const ushort* __restrict__ K,
                                   ushort* KsBuf,
                                   int i, int kt, int w, int l,
                                   int lane15, int quad) {
    #pragma unroll
    for (int c = 0; c < 4; ++c) {
        int p = w * 4 + c;
        gld16(K + (size_t)i * 131072 + (size_t)(kt * 64 + (p >> 2) * 16 + lane15) * 128
                + (p & 3) * 32 + quad * 8,
              KsBuf + p * 512 + (size_t)l * 8);
    }
}

__global__ __launch_bounds__(256) void k_attn(const ushort* __restrict__ Q,
                                              const ushort* __restrict__ K,
                                              const ushort* __restrict__ Vtp,
                                              const int* __restrict__ tokens,
                                              ushort* __restrict__ ctx) {
    __shared__ ushort Ks[2][16 * 512];   // 32 KB double-buffered K planes
    __shared__ ushort Ps[4 * 1088];      // 8.7 KB, per-wave single group
    __shared__ ushort Msk[CL];           // 2 KB, bf16 additive mask
    const int i = blockIdx.x, qb = blockIdx.y * 128;
    const int t = threadIdx.x, w = t >> 6, l = t & 63;
    const int lane15 = l & 15, quad = l >> 4;

    {
        const int* tokb = tokens + (i & 7) * CL;   // faithful: mask batch = i % B
        #pragma unroll
        for (int jj = 0; jj < 4; ++jj) {
            int idx = t + 256 * jj;
            Msk[idx] = (tokb[idx] == 0) ? (ushort)0xFF80 : (ushort)0;  // -inf / 0
        }
    }
    short8 af[2][4];
    #pragma unroll
    for (int g = 0; g < 2; ++g)
        #pragma unroll
        for (int kc = 0; kc < 4; ++kc)
            af[g][kc] = *(const short8*)&Q[(size_t)i * 131072
                + (size_t)(qb + w * 32 + g * 16 + lane15) * 128 + kc * 32 + quad * 8];

    f32x4 oacc[2][8];
    #pragma unroll
    for (int g = 0; g < 2; ++g)
        #pragma unroll
        for (int dt = 0; dt < 8; ++dt) oacc[g][dt] = f32x4{0.f, 0.f, 0.f, 0.f};
    float lsum[2][4] = {};
    const int wbase = w * 1088;
    const ushort* vtb = Vtp + (size_t)i * 131072 + (size_t)l * 8;   // per-lane V base

    attn_stageK(K, Ks[0], i, 0, w, l, lane15, quad);
    __syncthreads();                                 // drains stage (vmcnt 0)

    for (int kt = 0; kt < 16; ++kt) {
        const int cur = kt & 1;
        if (kt < 15)
            attn_stageK(K, Ks[cur ^ 1], i, kt + 1, w, l, lane15, quad);

        // QK^T: 16 K-plane reads shared across both q-groups
        f32x4 sc[2][4];
        __builtin_amdgcn_s_setprio(1);
        #pragma unroll
        for (int j = 0; j < 4; ++j) {
            short8 bk[4];
            #pragma unroll
            for (int kc = 0; kc < 4; ++kc)
                bk[kc] = *(const short8*)&Ks[cur][(j * 4 + kc) * 512 + l * 8];
            #pragma unroll
            for (int g = 0; g < 2; ++g) {
                sc[g][j] = f32x4{0.f, 0.f, 0.f, 0.f};
                #pragma unroll
                for (int kc = 0; kc < 4; ++kc)
                    sc[g][j] = __builtin_amdgcn_mfma_f32_16x16x32_bf16(af[g][kc], bk[kc], sc[g][j], 0, 0, 0);
            }
        }
        __builtin_amdgcn_s_setprio(0);
        // scale + mask + exp (no max: scores bounded), per-lane partial sums
        #pragma unroll
        for (int j = 0; j < 4; ++j) {
            float mj = b2f(Msk[kt * 64 + j * 16 + lane15]);
            #pragma unroll
            for (int g = 0; g < 2; ++g)
                #pragma unroll
                for (int r = 0; r < 4; ++r) {
                    float pv = __expf(fmaf(sc[g][j][r], CSCALE, mj));
                    sc[g][j][r] = pv;
                    lsum[g][r] += pv;
                }
        }
        // P (C-layout) -> per-wave A-layout buffer, group-sequential
        short8 ap[2][2];
        #pragma unroll
        for (int g = 0; g < 2; ++g) {
            #pragma unroll
            for (int j = 0; j < 4; ++j) {
                int ks2 = j >> 1;
                int qq  = (j & 1) * 2 + (lane15 >> 3);
                int pos = lane15 & 7;
                #pragma unroll
                for (int r = 0; r < 4; ++r) {
                    union { float f; unsigned u; } cv; cv.f = sc[g][j][r];
                    Ps[wbase + ks2 * 544 + qq * 136 + (quad * 4 + r) * 8 + pos] =
                        (ushort)(cv.u >> 16);
                }
            }
            #pragma unroll
            for (int ks2 = 0; ks2 < 2; ++ks2)   // per-wave RAW: compiler waits
                ap[g][ks2] = *(const short8*)&Ps[wbase + ks2 * 544 + quad * 136 + lane15 * 8];
        }
        // PV: V planes straight from global (L2-resident, per-lane linear)
        const ushort* vkt = vtb + (size_t)kt * 16 * 512;
        __builtin_amdgcn_s_setprio(1);
        #pragma unroll
        for (int dt = 0; dt < 8; ++dt)
            #pragma unroll
            for (int ks2 = 0; ks2 < 2; ++ks2) {
                short8 bv = *(const short8*)(vkt + (dt * 2 + ks2) * 512);
                #pragma unroll
                for (int g = 0; g < 2; ++g)
                    oacc[g][dt] = __builtin_amdgcn_mfma_f32_16x16x32_bf16(ap[g][ks2], bv, oacc[g][dt], 0, 0, 0);
            }
        __builtin_amdgcn_s_setprio(0);
        __syncthreads();   // K stage for kt+1 drained; all K reads of cur done
    }
    // final row-sum reduction (across lane15) and normalize
    #pragma unroll
    for (int g = 0; g < 2; ++g) {
        float inv[4];
        #pragma unroll
        for (int r = 0; r < 4; ++r) {
            float s = lsum[g][r];
            #pragma unroll
            for (int off = 1; off < 16; off <<= 1) s += __shfl_xor(s, off);
            inv[r] = 1.f / s;
        }
        #pragma unroll
        for (int dt = 0; dt < 8; ++dt)
            #pragma unroll
            for (int r = 0; r < 4; ++r) {
                int q = qb + w * 32 + g * 16 + quad * 4 + r;
                ctx[(size_t)i * 131072 + (size_t)q * 128 + dt * 16 + lane15] =
                    f2b(oacc[g][dt][r] * inv[r]);
            }
    }
}

// ---------------------------------------------------------------- pooling ---
// pmax/psum hold 8 chunks (128 rows each) per batch, from k_gemm_out.
__global__ __launch_bounds__(1024) void k_pool2(const float* __restrict__ pmax,
                                                const float* __restrict__ psum,
                                                const float* __restrict__ gamma,
                                                const float* __restrict__ beta,
                                                float* __restrict__ out) {
    __shared__ float rs[16], rq[16];
    __shared__ float s_mu, s_inv;
    const int b = blockIdx.x;
    const int d = threadIdx.x;
    float mx = -3.4e38f, sm = 0.f;
    #pragma unroll
    for (int c = 0; c < 8; ++c) {
        size_t off = ((size_t)b * 8 + c) * CD + d;
        mx = fmaxf(mx, pmax[off]);
        sm += psum[off];
    }
    const float a0 = mx;
    const float a1 = sm * (1.0f / 1024.0f);
    float s = a0 + a1;
    float qd = a0 * a0 + a1 * a1;
    #pragma unroll
    for (int off = 32; off > 0; off >>= 1) {
        s  += __shfl_xor(s, off);
        qd += __shfl_xor(qd, off);
    }
    const int wid = d >> 6;
    if ((d & 63) == 0) { rs[wid] = s; rq[wid] = qd; }
    __syncthreads();
    if (d == 0) {
        float S = 0.f, Qm = 0.f;
        for (int ww = 0; ww < 16; ++ww) { S += rs[ww]; Qm += rq[ww]; }
        float mu  = S * (1.0f / 2048.0f);
        float var = Qm * (1.0f / 2048.0f) - mu * mu;
        s_mu = mu; s_inv = 1.0f / sqrtf(var + CEPS);
    }
    __syncthreads();
    const float mu = s_mu, inv = s_inv;
    out[(size_t)b * 2048 + d]        = (a0 - mu) * inv * gamma[d]        + beta[d];
    out[(size_t)b * 2048 + 1024 + d] = (a1 - mu) * inv * gamma[1024 + d] + beta[1024 + d];
}

// ----------------------------------------------------------------- launch ---
extern "C" void kernel_launch(void* const* d_in, const int* in_sizes, int n_in,
                              void* d_out, int out_size, void* d_ws, size_t ws_size,
                              hipStream_t stream) {
    const int*   tokens = (const int*)d_in[0];
    const float* emb    = (const float*)d_in[1];
    const float* Wq     = (const float*)d_in[2];
    const float* bq     = (const float*)d_in[3];
    const float* Wk     = (const float*)d_in[4];
    const float* bk     = (const float*)d_in[5];
    const float* Wv     = (const float*)d_in[6];
    const float* bv     = (const float*)d_in[7];
    const float* Wo     = (const float*)d_in[8];
    const float* bo     = (const float*)d_in[9];
    const float* gamma  = (const float*)d_in[10];
    const float* beta   = (const float*)d_in[11];
    float* out = (float*)d_out;

    char* p = (char*)d_ws;
    ushort* xb  = (ushort*)p;  p += (size_t)CM * CD * 2;
    ushort* wqt = (ushort*)p;  p += (size_t)CD * CD * 2;   // wq|wk|wv|wo contiguous
    ushort* wkt = (ushort*)p;  p += (size_t)CD * CD * 2;
    ushort* wvt = (ushort*)p;  p += (size_t)CD * CD * 2;
    ushort* wot = (ushort*)p;  p += (size_t)CD * CD * 2;
    ushort* qb_ = (ushort*)p;  p += (size_t)CM * CD * 2;    // q,k,v contiguous
    ushort* kb_ = (ushort*)p;  p += (size_t)CM * CD * 2;
    ushort* vb_ = (ushort*)p;  p += (size_t)CM * CD * 2;
    ushort* Vtp = (ushort*)p;  p += (size_t)CM * CD * 2;
    float*  pmax = (float*)p;  p += (size_t)CB * 8 * CD * 4;
    float*  psum = (float*)p;  p += (size_t)CB * 8 * CD * 4;
    ushort* ctx = vb_;           // alias (v row-major consumed by vtransp)
    (void)wkt; (void)wvt;

    k_gather<<<CM, 256, 0, stream>>>(tokens, emb, xb);

    dim3 wg(32, 32, 4);
    k_wtrans<<<wg, 256, 0, stream>>>(Wq, Wk, Wv, Wo, wqt);

    dim3 gq(CD / 128, CM / 128, 3);
    k_gemm_qkv<<<gq, 256, 0, stream>>>(xb, wqt, bq, bk, bv, qb_);

    k_vtransp<<<64 * 16, 256, 0, stream>>>(vb_, Vtp);

    dim3 ag(64, 8);                        // 512 blocks, 256 threads (4 waves)
    k_attn<<<ag, 256, 0, stream>>>(qb_, kb_, Vtp, tokens, ctx);

    dim3 go(CD / 128, CM / 128);
    k_gemm_out<<<go, 256, 0, stream>>>(ctx, wot, bo, tokens, emb, pmax, psum);

    k_pool2<<<CB, 1024, 0, stream>>>(pmax, psum, gamma, beta, out);
}

// Round 8
// 341.846 us; speedup vs baseline: 1.0566x; 1.0566x over previous
//
#include <hip/hip_runtime.h>
#include <math.h>

typedef __attribute__((ext_vector_type(8))) short short8;
typedef __attribute__((ext_vector_type(4))) float f32x4;

constexpr int CB = 8, CL = 1024, CD = 1024, CDH = 128, CM = 8192;
constexpr float CSCALE = 0.25f;   // (DH//H)^-0.5 = 16^-0.5
constexpr float CEPS = 1e-5f;

__device__ inline ushort f2b(float f) {
    union { float f; unsigned u; } v; v.f = f;
    unsigned r = v.u + 0x7FFF + ((v.u >> 16) & 1);   // RNE
    return (ushort)(r >> 16);
}
__device__ inline float b2f(ushort u) {
    union { unsigned u; float f; } v; v.u = ((unsigned)u) << 16;
    return v.f;
}

// async 16B/lane global->LDS (wave-uniform base + lane*16 dest)
__device__ inline void gld16(const void* g, void* l) {
    __builtin_amdgcn_global_load_lds(
        (const __attribute__((address_space(1))) void*)g,
        (__attribute__((address_space(3))) void*)l, 16, 0, 0);
}

// ---------------------------------------------------------------- gather ----
// Writes ONLY bf16 xb; the fp32 residual is re-gathered from emb in
// k_gemm_out (bit-identical: x[row] == emb[tokens[row]]).
__global__ __launch_bounds__(256) void k_gather(const int* __restrict__ tokens,
                                                const float* __restrict__ emb,
                                                ushort* __restrict__ xb) {
    int row = blockIdx.x;
    int tok = tokens[row];
    float4 v = ((const float4*)(emb + (size_t)tok * CD))[threadIdx.x];
    ushort4 o; o.x = f2b(v.x); o.y = f2b(v.y); o.z = f2b(v.z); o.w = f2b(v.w);
    ((ushort4*)(xb + (size_t)row * CD))[threadIdx.x] = o;
}

// -------------------------------------- weight transpose f32->bf16 (x4) -----
__global__ __launch_bounds__(256) void k_wtrans(const float* __restrict__ W0,
                                                const float* __restrict__ W1,
                                                const float* __restrict__ W2,
                                                const float* __restrict__ W3,
                                                ushort* __restrict__ Wt) {
    __shared__ float ws_[32][33];
    const int z = blockIdx.z;
    const float* W = (z == 0) ? W0 : ((z == 1) ? W1 : ((z == 2) ? W2 : W3));
    ushort* Wtz = Wt + (size_t)z * CD * CD;
    const int tk = blockIdx.x * 32, tn = blockIdx.y * 32;
    const int t = threadIdx.x;
    {
        int r = t >> 3, c4 = (t & 7) * 4;
        *(float4*)&ws_[r][c4] = *(const float4*)&W[(size_t)(tk + r) * CD + tn + c4];
    }
    __syncthreads();
    int n = t >> 3, k4 = (t & 7) * 4;
    ushort4 o;
    o.x = f2b(ws_[k4 + 0][n]); o.y = f2b(ws_[k4 + 1][n]);
    o.z = f2b(ws_[k4 + 2][n]); o.w = f2b(ws_[k4 + 3][n]);
    *(ushort4*)&Wtz[(size_t)(tn + n) * CD + tk + k4] = o;
}

// ---------------------------------------------------------- bf16 MFMA GEMM --
// R0-proven structure + R6-verified XCD remap (XCD = blockIdx.x owns 8
// m-tiles x all n: weights L2-resident per XCD, each A-panel fetched once).
__global__ __launch_bounds__(256) void k_gemm_qkv(const ushort* __restrict__ A,
                                                  const ushort* __restrict__ Wt3,
                                                  const float* __restrict__ b0,
                                                  const float* __restrict__ b1,
                                                  const float* __restrict__ b2,
                                                  ushort* __restrict__ C3) {
    __shared__ ushort As[128 * 32];
    __shared__ ushort Bs[128 * 32];
    const int z = blockIdx.z;
    const ushort* Bt  = Wt3 + (size_t)z * CD * CD;
    const float* bias = (z == 0) ? b0 : ((z == 1) ? b1 : b2);
    ushort* Cout      = C3 + (size_t)z * CM * CD;

    const int t = threadIdx.x, w = t >> 6, l = t & 63;
    const int lane15 = l & 15, quad = l >> 4;
    const int bm = (blockIdx.x * 8 + (blockIdx.y >> 3)) * 128;   // XCD-local A rows
    const int bn = (blockIdx.y & 7) * 128;                       // all n per XCD
    const int wm = (w >> 1) * 64, wn = (w & 1) * 64;
    const int arow = l >> 2;
    const int aseg = (l & 3) * 8;
    f32x4 acc[4][4] = {};

    for (int k0 = 0; k0 < CD; k0 += 32) {
        __syncthreads();
        #pragma unroll
        for (int c2 = 0; c2 < 2; ++c2) {
            int c = w * 2 + c2;
            gld16(A  + (size_t)(bm + c * 16 + arow) * CD + k0 + aseg, &As[c * 512 + l * 8]);
            gld16(Bt + (size_t)(bn + c * 16 + arow) * CD + k0 + aseg, &Bs[c * 512 + l * 8]);
        }
        __syncthreads();
        short8 af[4], bf[4];
        #pragma unroll
        for (int im = 0; im < 4; ++im)
            af[im] = *(const short8*)&As[(wm + im * 16 + lane15) * 32 + quad * 8];
        #pragma unroll
        for (int in = 0; in < 4; ++in)
            bf[in] = *(const short8*)&Bs[(wn + in * 16 + lane15) * 32 + quad * 8];
        #pragma unroll
        for (int im = 0; im < 4; ++im)
            #pragma unroll
            for (int in = 0; in < 4; ++in)
                acc[im][in] = __builtin_amdgcn_mfma_f32_16x16x32_bf16(af[im], bf[in], acc[im][in], 0, 0, 0);
    }
    #pragma unroll
    for (int in = 0; in < 4; ++in) {
        int col = bn + wn + in * 16 + lane15;
        float bv = bias[col];
        #pragma unroll
        for (int im = 0; im < 4; ++im) {
            int row0 = bm + wm + im * 16 + quad * 4;
            #pragma unroll
            for (int r = 0; r < 4; ++r)
                Cout[(size_t)(row0 + r) * CD + col] = f2b(acc[im][in][r] + bv);
        }
    }
}

// OUT-projection, fused residual/pooling epilogue. Residual is re-gathered
// from emb via a 128-entry token LUT (bit-identical to the old x buffer).
__global__ __launch_bounds__(256) void k_gemm_out(const ushort* __restrict__ A,
                                                  const ushort* __restrict__ Bt,
                                                  const float* __restrict__ bias,
                                                  const int* __restrict__ tokens,
                                                  const float* __restrict__ emb,
                                                  float* __restrict__ pmax,
                                                  float* __restrict__ psum) {
    __shared__ ushort As[128 * 32];
    __shared__ ushort Bs[128 * 32];
    __shared__ float redmx[4][64], redsm[4][64];
    __shared__ int tokL[128];
    const int t = threadIdx.x, w = t >> 6, l = t & 63;
    const int lane15 = l & 15, quad = l >> 4;
    const int bm = (blockIdx.x * 8 + (blockIdx.y >> 3)) * 128;
    const int bn = (blockIdx.y & 7) * 128;
    const int wm = (w >> 1) * 64, wn = (w & 1) * 64;
    const int arow = l >> 2;
    const int aseg = (l & 3) * 8;
    if (t < 128) tokL[t] = tokens[bm + t];   // covered by first k-loop barrier
    f32x4 acc[4][4] = {};

    for (int k0 = 0; k0 < CD; k0 += 32) {
        __syncthreads();
        #pragma unroll
        for (int c2 = 0; c2 < 2; ++c2) {
            int c = w * 2 + c2;
            gld16(A  + (size_t)(bm + c * 16 + arow) * CD + k0 + aseg, &As[c * 512 + l * 8]);
            gld16(Bt + (size_t)(bn + c * 16 + arow) * CD + k0 + aseg, &Bs[c * 512 + l * 8]);
        }
        __syncthreads();
        short8 af[4], bf[4];
        #pragma unroll
        for (int im = 0; im < 4; ++im)
            af[im] = *(const short8*)&As[(wm + im * 16 + lane15) * 32 + quad * 8];
        #pragma unroll
        for (int in = 0; in < 4; ++in)
            bf[in] = *(const short8*)&Bs[(wn + in * 16 + lane15) * 32 + quad * 8];
        #pragma unroll
        for (int im = 0; im < 4; ++im)
            #pragma unroll
            for (int in = 0; in < 4; ++in)
                acc[im][in] = __builtin_amdgcn_mfma_f32_16x16x32_bf16(af[im], bf[in], acc[im][in], 0, 0, 0);
    }
    // fused epilogue: per-column max/sum over this block's 128 rows
    const int by = bm >> 7, bb = by >> 3, chunk = by & 7;   // logical m-tile
    float vmax_[4], vsum_[4];
    #pragma unroll
    for (int in = 0; in < 4; ++in) {
        int col = bn + wn + in * 16 + lane15;
        float bvv = bias[col];
        float mx = -3.4e38f, sm = 0.f;
        #pragma unroll
        for (int im = 0; im < 4; ++im) {
            int rl0 = wm + im * 16 + quad * 4;
            #pragma unroll
            for (int r = 0; r < 4; ++r) {
                float rv = emb[(size_t)tokL[rl0 + r] * CD + col];
                float rel = acc[im][in][r] + bvv + rv;
                mx = fmaxf(mx, rel);
                sm += rel;
            }
        }
        mx = fmaxf(mx, __shfl_xor(mx, 16));   // reduce across quads: 64 rows/wave
        mx = fmaxf(mx, __shfl_xor(mx, 32));
        sm += __shfl_xor(sm, 16);
        sm += __shfl_xor(sm, 32);
        vmax_[in] = mx; vsum_[in] = sm;
    }
    if (l < 16) {
        #pragma unroll
        for (int in = 0; in < 4; ++in) {
            redmx[w][in * 16 + lane15] = vmax_[in];
            redsm[w][in * 16 + lane15] = vsum_[in];
        }
    }
    __syncthreads();
    if (t < 128) {                            // combine wave pairs {0,2},{1,3}
        int wcol = t >> 6, cc = t & 63;
        float m = fmaxf(redmx[wcol][cc], redmx[wcol + 2][cc]);
        float s = redsm[wcol][cc] + redsm[wcol + 2][cc];
        size_t off2 = ((size_t)bb * 8 + chunk) * CD + bn + wcol * 64 + cc;
        pmax[off2] = m;
        psum[off2] = s;
    }
}

// ----------------------------------- V -> fragment-ordered planes ----------
__global__ __launch_bounds__(256) void k_vtransp(const ushort* __restrict__ v,
                                                 ushort* __restrict__ Vtp) {
    __shared__ ushort Vs[64 * 136];
    const int i = blockIdx.x >> 4, kt = blockIdx.x & 15;
    const ushort* src = v + (size_t)i * 131072 + (size_t)kt * 64 * 128;
    const int t = threadIdx.x;
    #pragma unroll
    for (int ii = 0; ii < 4; ++ii) {
        int idx = t + 256 * ii;           // vec8 unit 0..1023
        int key = idx >> 4, seg = idx & 15;
        *(uint4*)&Vs[key * 136 + seg * 8] = *(const uint4*)&src[key * 128 + seg * 8];
    }
    __syncthreads();
    ushort* dst = Vtp + (size_t)blockIdx.x * 8192;   // 16 planes * 512
    #pragma unroll
    for (int it = 0; it < 4; ++it) {
        int L = t + 256 * it;             // line 0..1023 = p*64 + cell
        int cell = L & 63;
        int quadk = cell >> 4, l15 = cell & 15;
        int p = L >> 6;
        int d = (p >> 1) * 16 + l15;
        int kb = ((p & 1) * 4 + quadk) * 8;
        uint pk[4];
        #pragma unroll
        for (int jj = 0; jj < 4; ++jj) {
            uint lo = Vs[(kb + 2 * jj) * 136 + d];
            uint hi = Vs[(kb + 2 * jj + 1) * 136 + d];
            pk[jj] = lo | (hi << 16);
        }
        *(uint4*)&dst[(size_t)L * 8] = *(uint4*)pk;
    }
}

// ------------------------------------------------- flash MFMA attention -----
// R6 structure (4 waves x 32 q-rows, K AND V double-buffered in LDS,
// 1 barrier/kt, setprio on MFMA clusters). R7's V-direct-from-global
// regressed ~15us (4x L2 traffic + exposed latency) -- keep V in LDS.
__device__ inline void attn_stage(const ushort* __restrict__ K,
                                  const ushort* __restrict__ Vtp,
                                  ushort* KsBuf, ushort* VsBuf,
                                  int i, int kt, int w, int l,
                                  int lane15, int quad) {
    #pragma unroll
    for (int c = 0; c < 4; ++c) {
        int p = w * 4 + c;
        gld16(K + (size_t)i * 131072 + (size_t)(kt * 64 + (p >> 2) * 16 + lane15) * 128
                + (p & 3) * 32 + quad * 8,
              KsBuf + p * 512 + (size_t)l * 8);
        gld16(Vtp + ((size_t)(i * 16 + kt) * 16 + p) * 512 + (size_t)l * 8,
              VsBuf + p * 512 + (size_t)l * 8);
    }
}

__global__ __launch_bounds__(256) void k_attn(const ushort* __restrict__ Q,
                                              const ushort* __restrict__ K,
                                              const ushort* __restrict__ Vtp,
                                              const int* __restrict__ tokens,
                                              ushort* __restrict__ ctx) {
    __shared__ ushort Ks[2][16 * 512];   // 32 KB double-buffered K planes
    __shared__ ushort Vs[2][16 * 512];   // 32 KB double-buffered V planes
    __shared__ ushort Ps[4 * 1088];      // 8.7 KB, per-wave single group
    __shared__ ushort Msk[CL];           // 2 KB, bf16 additive mask
    const int i = blockIdx.x, qb = blockIdx.y * 128;
    const int t = threadIdx.x, w = t >> 6, l = t & 63;
    const int lane15 = l & 15, quad = l >> 4;

    {
        const int* tokb = tokens + (i & 7) * CL;   // faithful: mask batch = i % B
        #pragma unroll
        for (int jj = 0; jj < 4; ++jj) {
            int idx = t + 256 * jj;
            Msk[idx] = (tokb[idx] == 0) ? (ushort)0xFF80 : (ushort)0;  // -inf / 0
        }
    }
    short8 af[2][4];
    #pragma unroll
    for (int g = 0; g < 2; ++g)
        #pragma unroll
        for (int kc = 0; kc < 4; ++kc)
            af[g][kc] = *(const short8*)&Q[(size_t)i * 131072
                + (size_t)(qb + w * 32 + g * 16 + lane15) * 128 + kc * 32 + quad * 8];

    f32x4 oacc[2][8];
    #pragma unroll
    for (int g = 0; g < 2; ++g)
        #pragma unroll
        for (int dt = 0; dt < 8; ++dt) oacc[g][dt] = f32x4{0.f, 0.f, 0.f, 0.f};
    float lsum[2][4] = {};
    const int wbase = w * 1088;

    attn_stage(K, Vtp, Ks[0], Vs[0], i, 0, w, l, lane15, quad);
    __syncthreads();                                 // drains stage (vmcnt 0)

    for (int kt = 0; kt < 16; ++kt) {
        const int cur = kt & 1;
        if (kt < 15)
            attn_stage(K, Vtp, Ks[cur ^ 1], Vs[cur ^ 1], i, kt + 1, w, l, lane15, quad);

        // QK^T: 16 K-plane reads shared across both q-groups
        f32x4 sc[2][4];
        __builtin_amdgcn_s_setprio(1);
        #pragma unroll
        for (int j = 0; j < 4; ++j) {
            short8 bk[4];
            #pragma unroll
            for (int kc = 0; kc < 4; ++kc)
                bk[kc] = *(const short8*)&Ks[cur][(j * 4 + kc) * 512 + l * 8];
            #pragma unroll
            for (int g = 0; g < 2; ++g) {
                sc[g][j] = f32x4{0.f, 0.f, 0.f, 0.f};
                #pragma unroll
                for (int kc = 0; kc < 4; ++kc)
                    sc[g][j] = __builtin_amdgcn_mfma_f32_16x16x32_bf16(af[g][kc], bk[kc], sc[g][j], 0, 0, 0);
            }
        }
        __builtin_amdgcn_s_setprio(0);
        // scale + mask + exp (no max: scores bounded), per-lane partial sums
        #pragma unroll
        for (int j = 0; j < 4; ++j) {
            float mj = b2f(Msk[kt * 64 + j * 16 + lane15]);
            #pragma unroll
            for (int g = 0; g < 2; ++g)
                #pragma unroll
                for (int r = 0; r < 4; ++r) {
                    float pv = __expf(fmaf(sc[g][j][r], CSCALE, mj));
                    sc[g][j][r] = pv;
                    lsum[g][r] += pv;
                }
        }
        // P (C-layout) -> per-wave A-layout buffer, group-sequential
        short8 ap[2][2];
        #pragma unroll
        for (int g = 0; g < 2; ++g) {
            #pragma unroll
            for (int j = 0; j < 4; ++j) {
                int ks2 = j >> 1;
                int qq  = (j & 1) * 2 + (lane15 >> 3);
                int pos = lane15 & 7;
                #pragma unroll
                for (int r = 0; r < 4; ++r) {
                    union { float f; unsigned u; } cv; cv.f = sc[g][j][r];
                    Ps[wbase + ks2 * 544 + qq * 136 + (quad * 4 + r) * 8 + pos] =
                        (ushort)(cv.u >> 16);
                }
            }
            #pragma unroll
            for (int ks2 = 0; ks2 < 2; ++ks2)   // per-wave RAW: compiler waits
                ap[g][ks2] = *(const short8*)&Ps[wbase + ks2 * 544 + quad * 136 + lane15 * 8];
        }
        // PV: 16 V-plane reads shared across both q-groups
        __builtin_amdgcn_s_setprio(1);
        #pragma unroll
        for (int dt = 0; dt < 8; ++dt)
            #pragma unroll
            for (int ks2 = 0; ks2 < 2; ++ks2) {
                short8 bv = *(const short8*)&Vs[cur][(dt * 2 + ks2) * 512 + l * 8];
                #pragma unroll
                for (int g = 0; g < 2; ++g)
                    oacc[g][dt] = __builtin_amdgcn_mfma_f32_16x16x32_bf16(ap[g][ks2], bv, oacc[g][dt], 0, 0, 0);
            }
        __builtin_amdgcn_s_setprio(0);
        __syncthreads();   // stage for kt+1 drained; all reads of cur done
    }
    // final row-sum reduction (across lane15) and normalize
    #pragma unroll
    for (int g = 0; g < 2; ++g) {
        float inv[4];
        #pragma unroll
        for (int r = 0; r < 4; ++r) {
            float s = lsum[g][r];
            #pragma unroll
            for (int off = 1; off < 16; off <<= 1) s += __shfl_xor(s, off);
            inv[r] = 1.f / s;
        }
        #pragma unroll
        for (int dt = 0; dt < 8; ++dt)
            #pragma unroll
            for (int r = 0; r < 4; ++r) {
                int q = qb + w * 32 + g * 16 + quad * 4 + r;
                ctx[(size_t)i * 131072 + (size_t)q * 128 + dt * 16 + lane15] =
                    f2b(oacc[g][dt][r] * inv[r]);
            }
    }
}

// ---------------------------------------------------------------- pooling ---
// pmax/psum hold 8 chunks (128 rows each) per batch, from k_gemm_out.
__global__ __launch_bounds__(1024) void k_pool2(const float* __restrict__ pmax,
                                                const float* __restrict__ psum,
                                                const float* __restrict__ gamma,
                                                const float* __restrict__ beta,
                                                float* __restrict__ out) {
    __shared__ float rs[16], rq[16];
    __shared__ float s_mu, s_inv;
    const int b = blockIdx.x;
    const int d = threadIdx.x;
    float mx = -3.4e38f, sm = 0.f;
    #pragma unroll
    for (int c = 0; c < 8; ++c) {
        size_t off = ((size_t)b * 8 + c) * CD + d;
        mx = fmaxf(mx, pmax[off]);
        sm += psum[off];
    }
    const float a0 = mx;
    const float a1 = sm * (1.0f / 1024.0f);
    float s = a0 + a1;
    float qd = a0 * a0 + a1 * a1;
    #pragma unroll
    for (int off = 32; off > 0; off >>= 1) {
        s  += __shfl_xor(s, off);
        qd += __shfl_xor(qd, off);
    }
    const int wid = d >> 6;
    if ((d & 63) == 0) { rs[wid] = s; rq[wid] = qd; }
    __syncthreads();
    if (d == 0) {
        float S = 0.f, Qm = 0.f;
        for (int ww = 0; ww < 16; ++ww) { S += rs[ww]; Qm += rq[ww]; }
        float mu  = S * (1.0f / 2048.0f);
        float var = Qm * (1.0f / 2048.0f) - mu * mu;
        s_mu = mu; s_inv = 1.0f / sqrtf(var + CEPS);
    }
    __syncthreads();
    const float mu = s_mu, inv = s_inv;
    out[(size_t)b * 2048 + d]        = (a0 - mu) * inv * gamma[d]        + beta[d];
    out[(size_t)b * 2048 + 1024 + d] = (a1 - mu) * inv * gamma[1024 + d] + beta[1024 + d];
}

// ----------------------------------------------------------------- launch ---
extern "C" void kernel_launch(void* const* d_in, const int* in_sizes, int n_in,
                              void* d_out, int out_size, void* d_ws, size_t ws_size,
                              hipStream_t stream) {
    const int*   tokens = (const int*)d_in[0];
    const float* emb    = (const float*)d_in[1];
    const float* Wq     = (const float*)d_in[2];
    const float* bq     = (const float*)d_in[3];
    const float* Wk     = (const float*)d_in[4];
    const float* bk     = (const float*)d_in[5];
    const float* Wv     = (const float*)d_in[6];
    const float* bv     = (const float*)d_in[7];
    const float* Wo     = (const float*)d_in[8];
    const float* bo     = (const float*)d_in[9];
    const float* gamma  = (const float*)d_in[10];
    const float* beta   = (const float*)d_in[11];
    float* out = (float*)d_out;

    char* p = (char*)d_ws;
    ushort* xb  = (ushort*)p;  p += (size_t)CM * CD * 2;
    ushort* wqt = (ushort*)p;  p += (size_t)CD * CD * 2;   // wq|wk|wv|wo contiguous
    ushort* wkt = (ushort*)p;  p += (size_t)CD * CD * 2;
    ushort* wvt = (ushort*)p;  p += (size_t)CD * CD * 2;
    ushort* wot = (ushort*)p;  p += (size_t)CD * CD * 2;
    ushort* qb_ = (ushort*)p;  p += (size_t)CM * CD * 2;    // q,k,v contiguous
    ushort* kb_ = (ushort*)p;  p += (size_t)CM * CD * 2;
    ushort* vb_ = (ushort*)p;  p += (size_t)CM * CD * 2;
    ushort* Vtp = (ushort*)p;  p += (size_t)CM * CD * 2;
    float*  pmax = (float*)p;  p += (size_t)CB * 8 * CD * 4;
    float*  psum = (float*)p;  p += (size_t)CB * 8 * CD * 4;
    ushort* ctx = vb_;           // alias (v row-major consumed by vtransp)
    (void)wkt; (void)wvt;

    k_gather<<<CM, 256, 0, stream>>>(tokens, emb, xb);

    dim3 wg(32, 32, 4);
    k_wtrans<<<wg, 256, 0, stream>>>(Wq, Wk, Wv, Wo, wqt);

    dim3 gq(CD / 128, CM / 128, 3);
    k_gemm_qkv<<<gq, 256, 0, stream>>>(xb, wqt, bq, bk, bv, qb_);

    k_vtransp<<<64 * 16, 256, 0, stream>>>(vb_, Vtp);

    dim3 ag(64, 8);                        // 512 blocks, 256 threads (4 waves)
    k_attn<<<ag, 256, 0, stream>>>(qb_, kb_, Vtp, tokens, ctx);

    dim3 go(CD / 128, CM / 128);
    k_gemm_out<<<go, 256, 0, stream>>>(ctx, wot, bo, tokens, emb, pmax, psum);

    k_pool2<<<CB, 1024, 0, stream>>>(pmax, psum, gamma, beta, out);
}